// Round 5
// baseline (2712.943 us; speedup 1.0000x reference)
//
#include <hip/hip_runtime.h>

#define NN 2048
#define MM 2048
#define KC 8
#define DD 64
#define CPAD (2*NN*MM + NN*NN + MM*MM + 6*(NN+MM) + 256)
#define PADV 3.0e38f
#define LN2F    0.6931471805599453f
#define INVLN2F 1.4426950408889634f
#define PMAX 2064             // LDS potential buffer size (>= max cluster size 2048)

// zr layout (ints): [8..15]=cnt_x, [16..23]=cnt_y, [24..31]=fill_x, [32..39]=fill_y
struct Params {
  const float* x; const float* centers; const float* ftarg;
  const float* y; const int* predy;
  float* out;
  int* zr;
  int* pred_x;
  int* cntx; int* cnty; int* off_x; int* off_y;
  int* bxy; int* byx; int* bxx; int* byy;    // per-cluster segment bases in Call
  int* tpre;                                 // 33-entry tile prefix table
  float* la; float* lb; int* valid;
  float* Xp; float* Yp; float* xn; float* yn;
  float* Call;
};

__device__ __forceinline__ float wredsum(float v){
  #pragma unroll
  for(int m=32;m>=1;m>>=1) v += __shfl_xor(v,m,64);
  return v;
}

// ---------------- k_pred: kmeans predict + LDS-hist counts ----------------
__global__ void __launch_bounds__(256) k_pred(Params p){
  __shared__ int hx[KC], hy[KC];
  const int tid = threadIdx.x;
  const int gtid = blockIdx.x*blockDim.x + tid;
  const int nth  = gridDim.x*blockDim.x;

  if(tid<KC){ hx[tid]=0; hy[tid]=0; }
  __syncthreads();

  for(int i=gtid;i<NN;i+=nth){
    const float4* xi = (const float4*)(p.x + i*DD);
    float best = 3.4e38f; int bk = 0;
    for(int k=0;k<KC;k++){
      const float4* ck = (const float4*)(p.centers + k*DD);
      float s = 0.f;
      #pragma unroll
      for(int q=0;q<DD/4;q++){ float4 a=xi[q], b=ck[q];
        float dx=a.x-b.x, dy=a.y-b.y, dz=a.z-b.z, dw=a.w-b.w;
        s += dx*dx+dy*dy+dz*dz+dw*dw; }
      if(s < best){ best = s; bk = k; }
    }
    p.pred_x[i] = bk;
    atomicAdd(&hx[bk], 1);
  }
  for(int j=gtid;j<MM;j+=nth) atomicAdd(&hy[p.predy[j]], 1);
  __syncthreads();
  if(tid<KC   && hx[tid])    atomicAdd(&p.zr[8+tid], hx[tid]);
  if(tid>=KC && tid<2*KC && hy[tid-KC]) atomicAdd(&p.zr[16+tid-KC], hy[tid-KC]);
}

// ---------------- k_pack: redundant serial phase + block-reserved pack ----------------
__global__ void __launch_bounds__(256) k_pack(Params p){
  __shared__ int scx[KC], scy[KC];
  __shared__ int sox[KC+1], soy[KC+1];
  __shared__ int hbx[KC], hby[KC], basex[KC], basey[KC], curx[KC], cury[KC];
  const int tid = threadIdx.x;
  const int gtid = blockIdx.x*blockDim.x + tid;
  const int nth  = gridDim.x*blockDim.x;

  if(tid==0){
    int ox=0, oy=0; float lf=0.f;
    int sbxy[KC], sbyx[KC], sbxx[KC], sbyy[KC];
    for(int k=0;k<KC;k++){
      int nk=p.zr[8+k], mk=p.zr[16+k];
      scx[k]=nk; scy[k]=mk;
      sox[k]=ox; soy[k]=oy;
      ox+=nk; oy+=mk;
      float df = (float)nk/(float)NN - p.ftarg[k];
      lf += df*df;
    }
    sox[KC]=ox; soy[KC]=oy;
    int run=0;
    for(int k=0;k<KC;k++){ int nk=scx[k], mk=scy[k]; sbxy[k]=run; run+=nk*((mk+3)&~3); }
    for(int k=0;k<KC;k++){ int nk=scx[k], mk=scy[k]; sbyx[k]=run; run+=mk*((nk+3)&~3); }
    for(int k=0;k<KC;k++){ int nk=scx[k];            sbxx[k]=run; run+=nk*((nk+3)&~3); }
    for(int k=0;k<KC;k++){ int mk=scy[k];            sbyy[k]=run; run+=mk*((mk+3)&~3); }
    if(blockIdx.x==0){
      for(int k=0;k<KC;k++){
        int nk=scx[k], mk=scy[k];
        p.cntx[k]=nk; p.cnty[k]=mk;
        p.off_x[k]=sox[k]; p.off_y[k]=soy[k];
        p.bxy[k]=sbxy[k]; p.byx[k]=sbyx[k]; p.bxx[k]=sbxx[k]; p.byy[k]=sbyy[k];
        p.la[k] = -logf(fmaxf((float)nk,1.f));
        p.lb[k] = -logf(fmaxf((float)mk,1.f));
        p.valid[k] = (nk>0 && mk>0)?1:0;
      }
      int trun=0;
      for(int e=0;e<32;e++){
        int seg=e>>3, k=e&7;
        int nk=scx[k], mk=scy[k];
        int nrows = (seg==0)?nk:(seg==1)?mk:(seg==2)?nk:mk;
        int rs    = (seg==0)?((mk+3)&~3):(seg==1)?((nk+3)&~3):(seg==2)?((nk+3)&~3):((mk+3)&~3);
        p.tpre[e]=trun;
        trun += ((nrows+63)>>6) * ((rs+63)>>6);
      }
      p.tpre[32]=trun;
      p.out[0] = lf/(float)KC;    // filling loss; k_jobs atomicAdds the divergence on top
    }
  }
  if(tid<KC){ hbx[tid]=0; hby[tid]=0; curx[tid]=0; cury[tid]=0; }
  __syncthreads();

  // pass 1: this block's per-cluster counts (LDS atomics only)
  for(int i=gtid;i<NN;i+=nth) atomicAdd(&hbx[p.pred_x[i]],1);
  for(int j=gtid;j<MM;j+=nth) atomicAdd(&hby[p.predy[j]],1);
  __syncthreads();
  // reserve global ranges: ONE device atomic per (block,cluster)
  if(tid<KC){
    basex[tid] = sox[tid] + (hbx[tid] ? atomicAdd(&p.zr[24+tid], hbx[tid]) : 0);
    basey[tid] = soy[tid] + (hby[tid] ? atomicAdd(&p.zr[32+tid], hby[tid]) : 0);
  }
  __syncthreads();

  // pass 2: place points (LDS cursors; pack order within cluster is irrelevant)
  for(int i=gtid;i<NN;i+=nth){
    int k=p.pred_x[i];
    int pos = basex[k] + atomicAdd(&curx[k],1);
    const float4* xi=(const float4*)(p.x+i*DD);
    float4* dst=(float4*)(p.Xp+(size_t)pos*DD);
    float s=0.f;
    #pragma unroll
    for(int q=0;q<DD/4;q++){ float4 v=xi[q]; dst[q]=v;
      s += v.x*v.x+v.y*v.y+v.z*v.z+v.w*v.w; }
    p.xn[pos]=s;
  }
  for(int j=gtid;j<MM;j+=nth){
    int k=p.predy[j];
    int pos = basey[k] + atomicAdd(&cury[k],1);
    const float4* yj=(const float4*)(p.y+j*DD);
    float4* dst=(float4*)(p.Yp+(size_t)pos*DD);
    float s=0.f;
    #pragma unroll
    for(int q=0;q<DD/4;q++){ float4 v=yj[q]; dst[q]=v;
      s += v.x*v.x+v.y*v.y+v.z*v.z+v.w*v.w; }
    p.yn[pos]=s;
  }
}

// ---------------- k4: LDS-tiled cost build (64x64 tiles, B transposed) ----------------
__global__ void __launch_bounds__(256) k4_cost(Params p){
  __shared__ float As[64*68];
  __shared__ float Bt[64*68];
  const int tid = threadIdx.x;
  const int T = p.tpre[32];

  for(int tile=blockIdx.x; tile<T; tile+=gridDim.x){
    int e=0;
    for(int q=1;q<32;q++) if(tile>=p.tpre[q]) e=q;
    int seg=e>>3, k=e&7;
    int nk=p.cntx[k], mk=p.cnty[k];
    int rsx=(nk+3)&~3, rsy=(mk+3)&~3;
    const float *Apts, *Bpts, *nA, *nB; int nrows, ncol, rs, base;
    if(seg==0){ Apts=p.Xp+(size_t)p.off_x[k]*DD; Bpts=p.Yp+(size_t)p.off_y[k]*DD;
      nA=p.xn+p.off_x[k]; nB=p.yn+p.off_y[k]; nrows=nk; ncol=mk; rs=rsy; base=p.bxy[k]; }
    else if(seg==1){ Apts=p.Yp+(size_t)p.off_y[k]*DD; Bpts=p.Xp+(size_t)p.off_x[k]*DD;
      nA=p.yn+p.off_y[k]; nB=p.xn+p.off_x[k]; nrows=mk; ncol=nk; rs=rsx; base=p.byx[k]; }
    else if(seg==2){ Apts=p.Xp+(size_t)p.off_x[k]*DD; Bpts=Apts;
      nA=p.xn+p.off_x[k]; nB=nA; nrows=nk; ncol=nk; rs=rsx; base=p.bxx[k]; }
    else { Apts=p.Yp+(size_t)p.off_y[k]*DD; Bpts=Apts;
      nA=p.yn+p.off_y[k]; nB=nA; nrows=mk; ncol=mk; rs=rsy; base=p.byy[k]; }
    int ntc=(rs+63)>>6;
    int lt = tile - p.tpre[e];
    int tr = lt/ntc, tc = lt - tr*ntc;

    __syncthreads();
    for(int l=tid;l<1024;l+=256){
      int row=l>>4, c4=l&15;
      int gA=tr*64+row;
      float4 va = (gA<nrows)? ((const float4*)Apts)[gA*16+c4] : make_float4(0.f,0.f,0.f,0.f);
      *(float4*)&As[row*68 + c4*4] = va;
      int gB=tc*64+row;
      float4 vb = (gB<ncol)? ((const float4*)Bpts)[gB*16+c4] : make_float4(0.f,0.f,0.f,0.f);
      Bt[(c4*4+0)*68+row]=vb.x; Bt[(c4*4+1)*68+row]=vb.y;
      Bt[(c4*4+2)*68+row]=vb.z; Bt[(c4*4+3)*68+row]=vb.w;
    }
    __syncthreads();

    int tx=tid&15, ty=tid>>4;
    float4 acc[4] = {make_float4(0,0,0,0),make_float4(0,0,0,0),
                     make_float4(0,0,0,0),make_float4(0,0,0,0)};
    for(int kk=0;kk<64;kk+=4){
      float4 a0=*(float4*)&As[(ty*4+0)*68+kk];
      float4 a1=*(float4*)&As[(ty*4+1)*68+kk];
      float4 a2=*(float4*)&As[(ty*4+2)*68+kk];
      float4 a3=*(float4*)&As[(ty*4+3)*68+kk];
      float4 b0=*(float4*)&Bt[(kk+0)*68+tx*4];
      float4 b1=*(float4*)&Bt[(kk+1)*68+tx*4];
      float4 b2=*(float4*)&Bt[(kk+2)*68+tx*4];
      float4 b3=*(float4*)&Bt[(kk+3)*68+tx*4];
      #define ACCROW(i,AI) \
        acc[i].x = fmaf(AI.x,b0.x, fmaf(AI.y,b1.x, fmaf(AI.z,b2.x, fmaf(AI.w,b3.x, acc[i].x)))); \
        acc[i].y = fmaf(AI.x,b0.y, fmaf(AI.y,b1.y, fmaf(AI.z,b2.y, fmaf(AI.w,b3.y, acc[i].y)))); \
        acc[i].z = fmaf(AI.x,b0.z, fmaf(AI.y,b1.z, fmaf(AI.z,b2.z, fmaf(AI.w,b3.z, acc[i].z)))); \
        acc[i].w = fmaf(AI.x,b0.w, fmaf(AI.y,b1.w, fmaf(AI.z,b2.w, fmaf(AI.w,b3.w, acc[i].w))));
      ACCROW(0,a0) ACCROW(1,a1) ACCROW(2,a2) ACCROW(3,a3)
      #undef ACCROW
    }

    int gc0 = tc*64 + tx*4;
    #pragma unroll
    for(int i=0;i<4;i++){
      int gr = tr*64 + ty*4 + i;
      if(gr >= nrows) continue;
      float xr = nA[gr];
      float v[4]; float d[4]={acc[i].x,acc[i].y,acc[i].z,acc[i].w};
      #pragma unroll
      for(int j=0;j<4;j++){
        int gc = gc0+j;
        v[j] = PADV;
        if(gc < ncol) v[j] = 0.5f*fmaxf(xr + nB[gc] - 2.f*d[j], 0.f);
      }
      if(gc0+3 < rs){
        *(float4*)&p.Call[(size_t)base + (size_t)gr*rs + gc0] = make_float4(v[0],v[1],v[2],v[3]);
      } else {
        for(int j=0;j<4;j++) if(gc0+j < rs) p.Call[(size_t)base + (size_t)gr*rs + gc0+j] = v[j];
      }
    }
  }
}

// ---------------- k_jobs: cluster-local Sinkhorn, NO grid barrier ----------------
// 24 blocks = {xy-pair, xx, yy} x 8 clusters. The coupling matrix is
// block-diagonal per cluster (out-of-cluster log-weights are -1e9 == exact 0
// in fp32), so all iteration communication is LDS ping-pong + __syncthreads.
// Mapping: lane = row (64 rows/wave), scanning columns of the TRANSPOSED C
// segment (always exists: f-rows read byx, g-rows read bxy, xx/yy symmetric)
// -> coalesced global loads, uniform-address LDS broadcasts, and a pure
// in-lane online LSE (no cross-lane reduction at all).
__global__ void __launch_bounds__(1024, 1) k_jobs(Params p){
  __shared__ float PAb[2][PMAX];
  __shared__ float PBb[2][PMAX];
  __shared__ float red[16];
  const int tid  = threadIdx.x;
  const int lane = tid & 63;
  const int wv   = tid >> 6;          // 16 waves
  const int jt = blockIdx.x >> 3;     // 0=XY, 1=XX, 2=YY
  const int k  = blockIdx.x & 7;

  if(!p.valid[k]) return;             // block-uniform; contribution is 0

  const int nk = p.cntx[k], mk = p.cnty[k];
  const int rsx = (nk+3)&~3, rsy = (mk+3)&~3;
  const float la2 = p.la[k]*INVLN2F, lb2 = p.lb[k]*INVLN2F;

  // A-side / B-side job parameters (B-side only for XY)
  int RA, RB=0, colsA, colsB=0, csA, csB=0;
  const float *CA, *CB=nullptr;
  float hA, hB=0.f, fvA, fvB=0.f;
  if(jt==0){
    RA=nk; CA=p.Call+p.byx[k]; csA=rsx; colsA=mk; hA=lb2; fvA= 1.f/(float)nk;  // f-rows
    RB=mk; CB=p.Call+p.bxy[k]; csB=rsy; colsB=nk; hB=la2; fvB= 1.f/(float)mk;  // g-rows
  } else if(jt==1){
    RA=nk; CA=p.Call+p.bxx[k]; csA=rsx; colsA=nk; hA=la2; fvA=-1.f/(float)nk;  // f_aa
  } else {
    RA=mk; CA=p.Call+p.byy[k]; csA=rsy; colsA=mk; hA=lb2; fvA=-1.f/(float)mk;  // g_bb
  }
  const int TA=(RA+63)>>6, TB=(RB+63)>>6;

  for(int i=tid;i<PMAX;i+=1024){
    PAb[0][i]=0.f; PAb[1][i]=0.f; PBb[0][i]=0.f; PBb[1][i]=0.f;
  }
  __syncthreads();

  // in-lane online LSE over the row's columns (base-2 domain)
  auto scan = [&](const float* C, int cs, int cols, const float* src,
                  float h, float s1, int r, float& M, float& S){
    const float* Cr = C + r;
    float m=-3.4e38f, s=0.f;
    int c=0;
    for(; c+3<cols; c+=4){
      float4 pv = *(const float4*)&src[c];               // LDS broadcast
      float a0=fmaf(pv.x,s1,h), a1=fmaf(pv.y,s1,h);
      float a2=fmaf(pv.z,s1,h), a3=fmaf(pv.w,s1,h);
      float C0=Cr[(size_t)(c+0)*cs], C1=Cr[(size_t)(c+1)*cs];
      float C2=Cr[(size_t)(c+2)*cs], C3=Cr[(size_t)(c+3)*cs];
      float w0=fmaf(-C0,s1,a0), w1=fmaf(-C1,s1,a1);
      float w2=fmaf(-C2,s1,a2), w3=fmaf(-C3,s1,a3);
      float lm=fmaxf(fmaxf(w0,w1),fmaxf(w2,w3));
      float mn=fmaxf(m,lm);
      s = s*exp2f(m-mn) + ((exp2f(w0-mn)+exp2f(w1-mn)) + (exp2f(w2-mn)+exp2f(w3-mn)));
      m = mn;
    }
    for(; c<cols; c++){
      float w = fmaf(-Cr[(size_t)c*cs], s1, fmaf(src[c],s1,h));
      float mn=fmaxf(m,w);
      s = s*exp2f(m-mn) + exp2f(w-mn);
      m = mn;
    }
    M=m; S=s;
  };

  const double EMIND = 0.05*0.05, S2D = 0.8*0.8;
  double e = 16.0; int cur = 0;
  for(;;){
    const bool last = !(e > EMIND);
    const float eps = last ? (float)EMIND : (float)e;
    const float s1 = (1.0f/eps)*INVLN2F;
    const float* PAc=PAb[cur]; float* PAn=PAb[cur^1];
    const float* PBc=PBb[cur]; float* PBn=PBb[cur^1];

    for(int t=wv; t<TA+TB; t+=16){
      const bool isA = t < TA;
      const int rt = (isA? t : t-TA)<<6;
      const int r  = rt + lane;
      float m,s;
      if(isA) scan(CA, csA, colsA, (jt==0? PBc : PAc), hA, s1, r, m, s);
      else    scan(CB, csB, colsB, PAc,                hB, s1, r, m, s);
      float ft = -eps*LN2F*(m + log2f(s));
      if(isA){ if(r<RA) PAn[r] = 0.5f*(PAc[r] + ft); }
      else   { if(r<RB) PBn[r] = 0.5f*(PBc[r] + ft); }
    }
    __syncthreads();
    cur ^= 1;
    if(last) break;
    e *= S2D;
  }

  // ---- final extrapolation at eps_min with the post-loop potentials ----
  {
    const float eps = (float)EMIND;
    const float s1 = (1.0f/eps)*INVLN2F;
    const float* PAc=PAb[cur];
    const float* PBc=PBb[cur];
    float contrib = 0.f;
    for(int t=wv; t<TA+TB; t+=16){
      const bool isA = t < TA;
      const int rt = (isA? t : t-TA)<<6;
      const int r  = rt + lane;
      float m,s;
      if(isA) scan(CA, csA, colsA, (jt==0? PBc : PAc), hA, s1, r, m, s);
      else    scan(CB, csB, colsB, PAc,                hB, s1, r, m, s);
      float ft = -eps*LN2F*(m + log2f(s));
      if(isA){ if(r<RA) contrib += fvA*ft; }
      else   { if(r<RB) contrib += fvB*ft; }
    }
    contrib = wredsum(contrib);
    if(lane==0) red[wv] = contrib;
    __syncthreads();
    if(wv==0){
      float v = (lane<16)? red[lane] : 0.f;
      v = wredsum(v);
      if(lane==0) atomicAdd(p.out, v);
    }
  }
}

extern "C" void kernel_launch(void* const* d_in, const int* in_sizes, int n_in,
                              void* d_out, int out_size, void* d_ws, size_t ws_size,
                              hipStream_t stream)
{
  Params p;
  p.x       = (const float*)d_in[0];
  p.centers = (const float*)d_in[1];
  p.ftarg   = (const float*)d_in[2];
  p.y       = (const float*)d_in[3];
  p.predy   = (const int*)d_in[4];
  p.out     = (float*)d_out;

  char* w = (char*)d_ws; size_t o = 0;
  auto A = [&](size_t bytes)->char*{ char* r = w + o; o = (o + bytes + 255) & ~(size_t)255; return r; };
  p.zr   =(int*)A(64*4);
  p.pred_x=(int*)A(NN*4);
  p.cntx =(int*)A(KC*4); p.cnty=(int*)A(KC*4);
  p.off_x=(int*)A(KC*4); p.off_y=(int*)A(KC*4);
  p.bxy  =(int*)A(KC*4); p.byx =(int*)A(KC*4);
  p.bxx  =(int*)A(KC*4); p.byy =(int*)A(KC*4);
  p.tpre =(int*)A(33*4);
  p.la=(float*)A(KC*4); p.lb=(float*)A(KC*4); p.valid=(int*)A(KC*4);
  p.Xp=(float*)A((size_t)NN*DD*4); p.Yp=(float*)A((size_t)MM*DD*4);
  p.xn=(float*)A(NN*4); p.yn=(float*)A(MM*4);
  p.Call=(float*)A((size_t)CPAD*4);

  hipMemsetAsync(p.zr, 0, 64*4, stream);
  hipLaunchKernelGGL(k_pred,  dim3(16),  dim3(256),  0, stream, p);
  hipLaunchKernelGGL(k_pack,  dim3(32),  dim3(256),  0, stream, p);
  hipLaunchKernelGGL(k4_cost, dim3(512), dim3(256),  0, stream, p);
  hipLaunchKernelGGL(k_jobs,  dim3(24),  dim3(1024), 0, stream, p);
}

// Round 6
// 1261.030 us; speedup vs baseline: 2.1514x; 2.1514x over previous
//
#include <hip/hip_runtime.h>

#define NN 2048
#define MM 2048
#define KC 8
#define DD 64
#define RUP(n) (((n)+31)&~31)
#define CPAD (2*NN*MM + NN*NN + MM*MM + 32*2*(NN+MM) + 1024)
#define PADV 3.0e38f
#define LN2F    0.6931471805599453f
#define INVLN2F 1.4426950408889634f
#define PSZ 2048              // per-(buffer,cluster) potential array size
#define FSTRIDE 16            // flag padding: one flag per 64B
#define NJB 256               // k_jobs blocks: 8 clusters x 32 slots

// zr layout (ints): [8..15]=cnt_x, [16..23]=cnt_y, [24..31]=fill_x, [32..39]=fill_y
struct Params {
  const float* x; const float* centers; const float* ftarg;
  const float* y; const int* predy;
  float* out;
  int* zr;
  int* pred_x;
  int* cntx; int* cnty; int* off_x; int* off_y;
  int* bxy; int* byx; int* bxx; int* byy;    // per-cluster segment bases in Call
  int* tpre;                                 // 33-entry tile prefix table
  float* la; float* lb; int* valid; float* acc;
  float* part;                               // NJB per-block partials
  float* Xp; float* Yp; float* xn; float* yn;
  float* Fab; float* Gab; float* Faa; float* Gbb;  // each [2][KC][PSZ], contiguous from Fab
  int* bsync;                                // [64 + bid*FSTRIDE] arrival flags (monotone)
  float* Call;
};

__device__ __forceinline__ float wredsum(float v){
  #pragma unroll
  for(int m=32;m>=1;m>>=1) v += __shfl_xor(v,m,64);
  return v;
}

// coherent (LLC-resident, L1/L2-bypassing) ops — all cross-block data uses these.
__device__ __forceinline__ void st_coh(float* a, float v){
  __hip_atomic_store(a, v, __ATOMIC_RELAXED, __HIP_MEMORY_SCOPE_AGENT);
}
__device__ __forceinline__ float ld_coh(const float* a){
  return __hip_atomic_load(a, __ATOMIC_RELAXED, __HIP_MEMORY_SCOPE_AGENT);
}
__device__ __forceinline__ void st_flag(int* a, int v){
  __hip_atomic_store(a, v, __ATOMIC_RELAXED, __HIP_MEMORY_SCOPE_AGENT);
}
__device__ __forceinline__ int ld_flag(const int* a){
  return __hip_atomic_load(a, __ATOMIC_RELAXED, __HIP_MEMORY_SCOPE_AGENT);
}
__device__ __forceinline__ float4 ld_cohx4(const float* a){
  float4 r;
  asm volatile("global_load_dwordx4 %0, %1, off sc0 sc1\n\t"
               "s_waitcnt vmcnt(0)"
               : "=&v"(r) : "v"(a) : "memory");
  return r;
}

// ---- per-cluster domain barrier (8 or 16 blocks; graph-capture-safe) ----
// entry __syncthreads drains vmcnt (sc0sc1 potential stores are at LLC) before
// tid0 publishes the arrival flag; wave 0 polls the domain's flags (one per
// lane); flags+data both bypass L1/L2 -> flag observation => data visibility.
__device__ __forceinline__ void dbar(int* bs, int k, int slotbase, int nb, int target){
  __syncthreads();
  if(threadIdx.x==0)
    st_flag(&bs[64 + blockIdx.x*FSTRIDE], target);
  if(threadIdx.x < 64){
    const int lane = threadIdx.x;
    const int* fp = &bs[64 + (k + 8*(slotbase + (lane<nb?lane:0)))*FSTRIDE];
    for(;;){
      int v = (lane<nb)? ld_flag(fp) : 0x7fffffff;
      if(__all(v >= target)) break;
      __builtin_amdgcn_s_sleep(2);
    }
  }
  __syncthreads();
}

// ---------------- k_pred: zero pots/flags/partials + kmeans predict + counts ----------------
__global__ void __launch_bounds__(256) k_pred(Params p){
  __shared__ int hx[KC], hy[KC];
  const int tid = threadIdx.x;
  const int gtid = blockIdx.x*blockDim.x + tid;
  const int nth  = gridDim.x*blockDim.x;

  if(tid<KC){ hx[tid]=0; hy[tid]=0; }
  __syncthreads();

  for(int i=gtid;i<8*KC*PSZ;i+=nth) p.Fab[i]=0.f;    // Fab..Gbb contiguous
  for(int i=gtid;i<64+NJB*FSTRIDE;i+=nth) p.bsync[i]=0;
  for(int i=gtid;i<NJB;i+=nth) p.part[i]=0.f;

  for(int i=gtid;i<NN;i+=nth){
    const float4* xi = (const float4*)(p.x + i*DD);
    float best = 3.4e38f; int bk = 0;
    for(int k=0;k<KC;k++){
      const float4* ck = (const float4*)(p.centers + k*DD);
      float s = 0.f;
      #pragma unroll
      for(int q=0;q<DD/4;q++){ float4 a=xi[q], b=ck[q];
        float dx=a.x-b.x, dy=a.y-b.y, dz=a.z-b.z, dw=a.w-b.w;
        s += dx*dx+dy*dy+dz*dz+dw*dw; }
      if(s < best){ best = s; bk = k; }
    }
    p.pred_x[i] = bk;
    atomicAdd(&hx[bk], 1);
  }
  for(int j=gtid;j<MM;j+=nth) atomicAdd(&hy[p.predy[j]], 1);
  __syncthreads();
  if(tid<KC   && hx[tid])    atomicAdd(&p.zr[8+tid], hx[tid]);
  if(tid>=KC && tid<2*KC && hy[tid-KC]) atomicAdd(&p.zr[16+tid-KC], hy[tid-KC]);
}

// ---------------- k_pack: redundant serial phase + block-reserved pack ----------------
__global__ void __launch_bounds__(256) k_pack(Params p){
  __shared__ int scx[KC], scy[KC];
  __shared__ int sox[KC+1], soy[KC+1];
  __shared__ int hbx[KC], hby[KC], basex[KC], basey[KC], curx[KC], cury[KC];
  const int tid = threadIdx.x;
  const int gtid = blockIdx.x*blockDim.x + tid;
  const int nth  = gridDim.x*blockDim.x;

  if(tid==0){
    int ox=0, oy=0; float lf=0.f;
    int sbxy[KC], sbyx[KC], sbxx[KC], sbyy[KC];
    for(int k=0;k<KC;k++){
      int nk=p.zr[8+k], mk=p.zr[16+k];
      scx[k]=nk; scy[k]=mk;
      sox[k]=ox; soy[k]=oy;
      ox+=nk; oy+=mk;
      float df = (float)nk/(float)NN - p.ftarg[k];
      lf += df*df;
    }
    sox[KC]=ox; soy[KC]=oy;
    int run=0;
    for(int k=0;k<KC;k++){ int nk=scx[k], mk=scy[k]; sbxy[k]=run; run+=nk*RUP(mk); }
    for(int k=0;k<KC;k++){ int nk=scx[k], mk=scy[k]; sbyx[k]=run; run+=mk*RUP(nk); }
    for(int k=0;k<KC;k++){ int nk=scx[k];            sbxx[k]=run; run+=nk*RUP(nk); }
    for(int k=0;k<KC;k++){ int mk=scy[k];            sbyy[k]=run; run+=mk*RUP(mk); }
    if(blockIdx.x==0){
      for(int k=0;k<KC;k++){
        int nk=scx[k], mk=scy[k];
        p.cntx[k]=nk; p.cnty[k]=mk;
        p.off_x[k]=sox[k]; p.off_y[k]=soy[k];
        p.bxy[k]=sbxy[k]; p.byx[k]=sbyx[k]; p.bxx[k]=sbxx[k]; p.byy[k]=sbyy[k];
        p.la[k] = -logf(fmaxf((float)nk,1.f));
        p.lb[k] = -logf(fmaxf((float)mk,1.f));
        p.valid[k] = (nk>0 && mk>0)?1:0;
      }
      int trun=0;
      for(int e=0;e<32;e++){
        int seg=e>>3, k=e&7;
        int nk=scx[k], mk=scy[k];
        int nrows = (seg==0)?nk:(seg==1)?mk:(seg==2)?nk:mk;
        int rs    = (seg==0)?RUP(mk):(seg==1)?RUP(nk):(seg==2)?RUP(nk):RUP(mk);
        p.tpre[e]=trun;
        trun += ((nrows+63)>>6) * ((rs+63)>>6);
      }
      p.tpre[32]=trun;
      *p.acc = lf/(float)KC;
    }
  }
  if(tid<KC){ hbx[tid]=0; hby[tid]=0; curx[tid]=0; cury[tid]=0; }
  __syncthreads();

  // pass 1: this block's per-cluster counts (LDS atomics only)
  for(int i=gtid;i<NN;i+=nth) atomicAdd(&hbx[p.pred_x[i]],1);
  for(int j=gtid;j<MM;j+=nth) atomicAdd(&hby[p.predy[j]],1);
  __syncthreads();
  // reserve global ranges: ONE device atomic per (block,cluster)
  if(tid<KC){
    basex[tid] = sox[tid] + (hbx[tid] ? atomicAdd(&p.zr[24+tid], hbx[tid]) : 0);
    basey[tid] = soy[tid] + (hby[tid] ? atomicAdd(&p.zr[32+tid], hby[tid]) : 0);
  }
  __syncthreads();

  // pass 2: place points (pack order within cluster is irrelevant)
  for(int i=gtid;i<NN;i+=nth){
    int k=p.pred_x[i];
    int pos = basex[k] + atomicAdd(&curx[k],1);
    const float4* xi=(const float4*)(p.x+i*DD);
    float4* dst=(float4*)(p.Xp+(size_t)pos*DD);
    float s=0.f;
    #pragma unroll
    for(int q=0;q<DD/4;q++){ float4 v=xi[q]; dst[q]=v;
      s += v.x*v.x+v.y*v.y+v.z*v.z+v.w*v.w; }
    p.xn[pos]=s;
  }
  for(int j=gtid;j<MM;j+=nth){
    int k=p.predy[j];
    int pos = basey[k] + atomicAdd(&cury[k],1);
    const float4* yj=(const float4*)(p.y+j*DD);
    float4* dst=(float4*)(p.Yp+(size_t)pos*DD);
    float s=0.f;
    #pragma unroll
    for(int q=0;q<DD/4;q++){ float4 v=yj[q]; dst[q]=v;
      s += v.x*v.x+v.y*v.y+v.z*v.z+v.w*v.w; }
    p.yn[pos]=s;
  }
}

// ---------------- k4: LDS-tiled cost build (64x64 tiles, B transposed) ----------------
__global__ void __launch_bounds__(256) k4_cost(Params p){
  __shared__ float As[64*68];
  __shared__ float Bt[64*68];
  const int tid = threadIdx.x;
  const int T = p.tpre[32];

  for(int tile=blockIdx.x; tile<T; tile+=gridDim.x){
    int e=0;
    for(int q=1;q<32;q++) if(tile>=p.tpre[q]) e=q;
    int seg=e>>3, k=e&7;
    int nk=p.cntx[k], mk=p.cnty[k];
    int rsx=RUP(nk), rsy=RUP(mk);
    const float *Apts, *Bpts, *nA, *nB; int nrows, ncol, rs, base;
    if(seg==0){ Apts=p.Xp+(size_t)p.off_x[k]*DD; Bpts=p.Yp+(size_t)p.off_y[k]*DD;
      nA=p.xn+p.off_x[k]; nB=p.yn+p.off_y[k]; nrows=nk; ncol=mk; rs=rsy; base=p.bxy[k]; }
    else if(seg==1){ Apts=p.Yp+(size_t)p.off_y[k]*DD; Bpts=p.Xp+(size_t)p.off_x[k]*DD;
      nA=p.yn+p.off_y[k]; nB=p.xn+p.off_x[k]; nrows=mk; ncol=nk; rs=rsx; base=p.byx[k]; }
    else if(seg==2){ Apts=p.Xp+(size_t)p.off_x[k]*DD; Bpts=Apts;
      nA=p.xn+p.off_x[k]; nB=nA; nrows=nk; ncol=nk; rs=rsx; base=p.bxx[k]; }
    else { Apts=p.Yp+(size_t)p.off_y[k]*DD; Bpts=Apts;
      nA=p.yn+p.off_y[k]; nB=nA; nrows=mk; ncol=mk; rs=rsy; base=p.byy[k]; }
    int ntc=(rs+63)>>6;
    int lt = tile - p.tpre[e];
    int tr = lt/ntc, tc = lt - tr*ntc;

    __syncthreads();
    for(int l=tid;l<1024;l+=256){
      int row=l>>4, c4=l&15;
      int gA=tr*64+row;
      float4 va = (gA<nrows)? ((const float4*)Apts)[gA*16+c4] : make_float4(0.f,0.f,0.f,0.f);
      *(float4*)&As[row*68 + c4*4] = va;
      int gB=tc*64+row;
      float4 vb = (gB<ncol)? ((const float4*)Bpts)[gB*16+c4] : make_float4(0.f,0.f,0.f,0.f);
      Bt[(c4*4+0)*68+row]=vb.x; Bt[(c4*4+1)*68+row]=vb.y;
      Bt[(c4*4+2)*68+row]=vb.z; Bt[(c4*4+3)*68+row]=vb.w;
    }
    __syncthreads();

    int tx=tid&15, ty=tid>>4;
    float4 acc[4] = {make_float4(0,0,0,0),make_float4(0,0,0,0),
                     make_float4(0,0,0,0),make_float4(0,0,0,0)};
    for(int kk=0;kk<64;kk+=4){
      float4 a0=*(float4*)&As[(ty*4+0)*68+kk];
      float4 a1=*(float4*)&As[(ty*4+1)*68+kk];
      float4 a2=*(float4*)&As[(ty*4+2)*68+kk];
      float4 a3=*(float4*)&As[(ty*4+3)*68+kk];
      float4 b0=*(float4*)&Bt[(kk+0)*68+tx*4];
      float4 b1=*(float4*)&Bt[(kk+1)*68+tx*4];
      float4 b2=*(float4*)&Bt[(kk+2)*68+tx*4];
      float4 b3=*(float4*)&Bt[(kk+3)*68+tx*4];
      #define ACCROW(i,AI) \
        acc[i].x = fmaf(AI.x,b0.x, fmaf(AI.y,b1.x, fmaf(AI.z,b2.x, fmaf(AI.w,b3.x, acc[i].x)))); \
        acc[i].y = fmaf(AI.x,b0.y, fmaf(AI.y,b1.y, fmaf(AI.z,b2.y, fmaf(AI.w,b3.y, acc[i].y)))); \
        acc[i].z = fmaf(AI.x,b0.z, fmaf(AI.y,b1.z, fmaf(AI.z,b2.z, fmaf(AI.w,b3.z, acc[i].z)))); \
        acc[i].w = fmaf(AI.x,b0.w, fmaf(AI.y,b1.w, fmaf(AI.z,b2.w, fmaf(AI.w,b3.w, acc[i].w))));
      ACCROW(0,a0) ACCROW(1,a1) ACCROW(2,a2) ACCROW(3,a3)
      #undef ACCROW
    }

    int gc0 = tc*64 + tx*4;
    #pragma unroll
    for(int i=0;i<4;i++){
      int gr = tr*64 + ty*4 + i;
      if(gr >= nrows) continue;
      float xr = nA[gr];
      float v[4]; float d[4]={acc[i].x,acc[i].y,acc[i].z,acc[i].w};
      #pragma unroll
      for(int j=0;j<4;j++){
        int gc = gc0+j;
        v[j] = PADV;
        if(gc < ncol) v[j] = 0.5f*fmaxf(xr + nB[gc] - 2.f*d[j], 0.f);
      }
      if(gc0+3 < rs){
        *(float4*)&p.Call[(size_t)base + (size_t)gr*rs + gc0] = make_float4(v[0],v[1],v[2],v[3]);
      } else {
        for(int j=0;j<4;j++) if(gc0+j < rs) p.Call[(size_t)base + (size_t)gr*rs + gc0+j] = v[j];
      }
    }
  }
}

// online-LSE over one float4 (base-2 domain)
#define LSE4(cv,pv,h2,m,s,s1) { \
  float w0=fmaf((pv).x-(cv).x,s1,h2), w1=fmaf((pv).y-(cv).y,s1,h2); \
  float w2=fmaf((pv).z-(cv).z,s1,h2), w3=fmaf((pv).w-(cv).w,s1,h2); \
  float lm=fmaxf(fmaxf(w0,w1),fmaxf(w2,w3)); \
  float mn=fmaxf(m,lm); \
  s = s*exp2f(m-mn) + ((exp2f(w0-mn)+exp2f(w1-mn))+(exp2f(w2-mn)+exp2f(w3-mn))); \
  m = mn; }

// ---------------- k_jobs: cluster-local Sinkhorn at full width ----------------
// 256 blocks = 8 clusters x 32 slots; slot: [0,8)=xy-f, [8,16)=xy-g, [16,24)=xx,
// [24,32)=yy. Sync domains are per-cluster: xy = 16 blocks, xx/yy = 8 blocks.
// Cluster k's blocks are all == k (mod 8) -> same XCD by round-robin dispatch
// (speed-only: C reads become XCD-L2/L1-local; correctness uses agent scope).
// Each block owns 32 contiguous rows; 8 lanes cooperate per row (coalesced
// 128B C reads). Opposite potentials are batch-refreshed into LDS per
// iteration; updated potentials go to LLC via sc0sc1 stores.
__global__ void __launch_bounds__(256) k_jobs(Params p){
  __shared__ __align__(16) float Pl[PSZ];
  __shared__ float red[4];
  const int tid = threadIdx.x;
  const int lane = tid & 63;
  const int wv = tid >> 6;
  const int grp = tid >> 3;           // 0..31: row group
  const int sub = tid & 7;            // 0..7: column slice within row
  const int k = blockIdx.x & 7;
  const int slot = blockIdx.x >> 3;

  if(!p.valid[k]) return;             // whole domain returns -> no deadlock

  int side, s8, slotbase, nb;
  if(slot<8)      { side=0; s8=slot;    slotbase=0;  nb=16; }
  else if(slot<16){ side=1; s8=slot-8;  slotbase=0;  nb=16; }
  else if(slot<24){ side=2; s8=slot-16; slotbase=16; nb=8;  }
  else            { side=3; s8=slot-24; slotbase=24; nb=8;  }

  const int nk=p.cntx[k], mk=p.cnty[k];
  const int rsx=RUP(nk), rsy=RUP(mk);
  const float la2=p.la[k]*INVLN2F, lb2=p.lb[k]*INVLN2F;

  const float *Cb; int cs, colsP, R; float *ownA, *oppA; float h2, fv;
  if(side==0){ Cb=p.Call+p.bxy[k]; cs=rsy; colsP=rsy; R=nk;
               ownA=p.Fab+k*PSZ; oppA=p.Gab+k*PSZ; h2=lb2; fv= 1.f/(float)nk; }
  else if(side==1){ Cb=p.Call+p.byx[k]; cs=rsx; colsP=rsx; R=mk;
               ownA=p.Gab+k*PSZ; oppA=p.Fab+k*PSZ; h2=la2; fv= 1.f/(float)mk; }
  else if(side==2){ Cb=p.Call+p.bxx[k]; cs=rsx; colsP=rsx; R=nk;
               ownA=p.Faa+k*PSZ; oppA=p.Faa+k*PSZ; h2=la2; fv=-1.f/(float)nk; }
  else        { Cb=p.Call+p.byy[k]; cs=rsy; colsP=rsy; R=mk;
               ownA=p.Gbb+k*PSZ; oppA=p.Gbb+k*PSZ; h2=lb2; fv=-1.f/(float)mk; }
  const int npass = (R + 255) >> 8;

  const double EMIND = 0.05*0.05, S2D = 0.8*0.8;
  double e = 16.0; int it = 0;
  for(;;){
    const bool last = !(e > EMIND);
    const float eps = last ? (float)EMIND : (float)e;
    const float s1 = (1.0f/eps)*INVLN2F;
    const int cur = it & 1;

    // refresh opposite potentials [cur] into LDS (<=2 coherent rounds)
    const float* Po = oppA + cur*(KC*PSZ);
    for(int i=tid; i*4<colsP; i+=256)
      *(float4*)&Pl[i*4] = ld_cohx4(Po + i*4);
    __syncthreads();

    const float* ownC = ownA + cur*(KC*PSZ);
    float*       ownN = ownA + (cur^1)*(KC*PSZ);
    for(int pass=0; pass<npass; ++pass){
      const int r = pass*256 + s8*32 + grp;
      if(r < R){
        const float* Crow = Cb + (size_t)r*cs;
        float m=-3.4e38f, s=0.f;
        for(int cf=4*sub; cf<colsP; cf+=32){
          float4 cv = *(const float4*)(Crow + cf);
          float4 pv = *(const float4*)&Pl[cf];
          LSE4(cv, pv, h2, m, s, s1)
        }
        #pragma unroll
        for(int msk=1; msk<8; msk<<=1){
          float om=__shfl_xor(m,msk), os=__shfl_xor(s,msk);
          float mn=fmaxf(m,om);
          s = s*exp2f(m-mn) + os*exp2f(om-mn);
          m = mn;
        }
        if(sub==0){
          float ft = -eps*LN2F*(m + log2f(s));
          float fo = ld_coh(ownC + r);
          st_coh(ownN + r, 0.5f*(fo + ft));
        }
      }
    }
    ++it;
    dbar(p.bsync, k, slotbase, nb, it);
    if(last) break;
    e *= S2D;
  }

  // ---- final extrapolation at eps_min (reads potentials from [it&1]) ----
  {
    const float eps = (float)EMIND;
    const float s1 = (1.0f/eps)*INVLN2F;
    const int cur = it & 1;
    const float* Po = oppA + cur*(KC*PSZ);
    for(int i=tid; i*4<colsP; i+=256)
      *(float4*)&Pl[i*4] = ld_cohx4(Po + i*4);
    __syncthreads();

    float acc = 0.f;
    for(int pass=0; pass<npass; ++pass){
      const int r = pass*256 + s8*32 + grp;
      float contrib = 0.f;
      if(r < R){
        const float* Crow = Cb + (size_t)r*cs;
        float m=-3.4e38f, s=0.f;
        for(int cf=4*sub; cf<colsP; cf+=32){
          float4 cv = *(const float4*)(Crow + cf);
          float4 pv = *(const float4*)&Pl[cf];
          LSE4(cv, pv, h2, m, s, s1)
        }
        #pragma unroll
        for(int msk=1; msk<8; msk<<=1){
          float om=__shfl_xor(m,msk), os=__shfl_xor(s,msk);
          float mn=fmaxf(m,om);
          s = s*exp2f(m-mn) + os*exp2f(om-mn);
          m = mn;
        }
        if(sub==0) contrib = fv * (-eps*LN2F*(m + log2f(s)));
      }
      acc += contrib;
    }
    acc = wredsum(acc);
    if(lane==0) red[wv] = acc;
    __syncthreads();
    if(tid==0) p.part[blockIdx.x] = red[0]+red[1]+red[2]+red[3];
  }
}

// ---------------- k_out: sum partials + filling loss ----------------
__global__ void __launch_bounds__(256) k_out(Params p){
  __shared__ float red[4];
  float s = p.part[threadIdx.x];
  s = wredsum(s);
  if((threadIdx.x&63)==0) red[threadIdx.x>>6]=s;
  __syncthreads();
  if(threadIdx.x==0)
    p.out[0] = red[0]+red[1]+red[2]+red[3] + *p.acc;
}

extern "C" void kernel_launch(void* const* d_in, const int* in_sizes, int n_in,
                              void* d_out, int out_size, void* d_ws, size_t ws_size,
                              hipStream_t stream)
{
  Params p;
  p.x       = (const float*)d_in[0];
  p.centers = (const float*)d_in[1];
  p.ftarg   = (const float*)d_in[2];
  p.y       = (const float*)d_in[3];
  p.predy   = (const int*)d_in[4];
  p.out     = (float*)d_out;

  char* w = (char*)d_ws; size_t o = 0;
  auto A = [&](size_t bytes)->char*{ char* r = w + o; o = (o + bytes + 255) & ~(size_t)255; return r; };
  p.zr   =(int*)A(64*4);
  p.pred_x=(int*)A(NN*4);
  p.cntx =(int*)A(KC*4); p.cnty=(int*)A(KC*4);
  p.off_x=(int*)A(KC*4); p.off_y=(int*)A(KC*4);
  p.bxy  =(int*)A(KC*4); p.byx =(int*)A(KC*4);
  p.bxx  =(int*)A(KC*4); p.byy =(int*)A(KC*4);
  p.tpre =(int*)A(33*4);
  p.la=(float*)A(KC*4); p.lb=(float*)A(KC*4); p.valid=(int*)A(KC*4);
  p.acc=(float*)A(4);
  p.part=(float*)A(NJB*4);
  p.Xp=(float*)A((size_t)NN*DD*4); p.Yp=(float*)A((size_t)MM*DD*4);
  p.xn=(float*)A(NN*4); p.yn=(float*)A(MM*4);
  float* pots=(float*)A((size_t)8*KC*PSZ*4);     // 4 arrays x [2][KC][PSZ], contiguous
  p.Fab=pots;            p.Gab=pots+2*KC*PSZ;
  p.Faa=pots+4*KC*PSZ;   p.Gbb=pots+6*KC*PSZ;
  p.bsync=(int*)A((64+NJB*FSTRIDE)*4);
  p.Call=(float*)A((size_t)CPAD*4);

  hipMemsetAsync(p.zr, 0, 64*4, stream);
  hipLaunchKernelGGL(k_pred,  dim3(16),  dim3(256), 0, stream, p);
  hipLaunchKernelGGL(k_pack,  dim3(32),  dim3(256), 0, stream, p);
  hipLaunchKernelGGL(k4_cost, dim3(512), dim3(256), 0, stream, p);
  hipLaunchKernelGGL(k_jobs,  dim3(NJB), dim3(256), 0, stream, p);
  hipLaunchKernelGGL(k_out,   dim3(1),   dim3(256), 0, stream, p);
}